// Round 19
// baseline (329.229 us; speedup 1.0000x reference)
//
#include <hip/hip_runtime.h>

#define N_N 100000
#define N_E 1600000
#define N_G 5000
#define HID 256
#define IND 14

#define NBUK 391      // buckets: dst>>8, 256 nodes each (391*256 = 100096)
#define CAP 5120      // static per-bucket capacity (E[cnt]=4096, sigma~64; +16 sigma)
#define CH3 8192      // edges per binning block (512 threads)
#define NFB 196       // ceil(N_E/CH3)

typedef __bf16 bf16x8 __attribute__((ext_vector_type(8)));
typedef float f32x4 __attribute__((ext_vector_type(4)));
typedef unsigned short u16;
typedef unsigned int u32;

// ---- workspace layout (units of 4 bytes) ----
constexpr size_t OFF_OUTS  = 0;          // float[5120]   (zeroed)
constexpr size_t OFF_GCUR  = 5120;       // int[391*16]   (zeroed, 64B-padded cursors)
constexpr size_t ZERO_END  = 11520;
constexpr size_t ZERO_BYTES = ZERO_END * 4;
constexpr size_t OFF_GCNT  = 11520;      // float[5120] (fully written)
constexpr size_t OFF_ROWP  = 16640;      // int[100096]
constexpr size_t OFF_DEG   = 116736;     // int[100096]
constexpr size_t OFF_EBUF  = 216832;     // u32[391*5120]
constexpr size_t OFF_CSRC  = 2218752;    // int[391*5120]
constexpr size_t OFF_H1B   = 4220672;    // bf16[100096*256] -> ends 17032960
constexpr size_t OFF_WCAT  = 17032960;   // bf16[256*512]    -> ends 17098496
constexpr size_t OFF_XP    = 17098496;   // bf16[N*16]       -> ends 17898496
constexpr size_t OFF_MEAN1B= 17898496;   // bf16[100096*256] -> ends 30710784
constexpr size_t OFF_W1CAT = 30710784;   // bf16[256*32]     -> ends 30714880
// end = 30714880 floats ~= 123 MB

__device__ __forceinline__ u32 f2b(float f) {
    u32 u = __float_as_uint(f);
    u32 r = u + 0x7FFFu + ((u >> 16) & 1u);
    return r >> 16;
}

#define ADD8(acc, v) do { \
    acc[0] += __uint_as_float(v.x << 16); \
    acc[1] += __uint_as_float(v.x & 0xFFFF0000u); \
    acc[2] += __uint_as_float(v.y << 16); \
    acc[3] += __uint_as_float(v.y & 0xFFFF0000u); \
    acc[4] += __uint_as_float(v.z << 16); \
    acc[5] += __uint_as_float(v.z & 0xFFFF0000u); \
    acc[6] += __uint_as_float(v.w << 16); \
    acc[7] += __uint_as_float(v.w & 0xFFFF0000u); \
} while (0)

// ---- MERGED binning + prep ----
#define PACK_N (N_N * 16)
#define WCAT_N (256 * 512)
#define W1CAT_N (256 * 32)
#define PREP_TOT (PACK_N + WCAT_N + W1CAT_N + N_G)
#define PREP_BLKS ((PREP_TOT + 511) / 512)      // 3407
__global__ __launch_bounds__(512) void k_bfill_prep(const int* __restrict__ ei, int* __restrict__ gcur,
                                                    u32* __restrict__ ebuf,
                                                    const float* __restrict__ x, const float* __restrict__ pos,
                                                    const int* __restrict__ batch,
                                                    const float* __restrict__ W2l, const float* __restrict__ W2r,
                                                    const float* __restrict__ W1l, const float* __restrict__ W1r,
                                                    u16* __restrict__ xpb, float* __restrict__ gcnt,
                                                    u16* __restrict__ wcat, u16* __restrict__ w1cat) {
    __shared__ int hist[NBUK];
    __shared__ int lcur[NBUK];
    __shared__ int gbase[NBUK];
    __shared__ int sc[512];
    __shared__ u32 stage[CH3];
    __shared__ u16 bstage[CH3];
    int t = threadIdx.x;
    if (blockIdx.x >= NFB) {
        int idx = (blockIdx.x - NFB) * 512 + t;
        if (idx < PACK_N) {
            int n = idx >> 4, f = idx & 15;
            float v = 0.f;
            if (f < 11) v = x[n * 11 + f];
            else if (f < 14) v = pos[n * 3 + (f - 11)];
            xpb[idx] = (u16)f2b(v);
        } else if (idx < PACK_N + WCAT_N) {
            int i2 = idx - PACK_N;
            int n = i2 >> 9, k = i2 & 511;
            float v = (k < 256) ? W2l[k * HID + n] : W2r[(k - 256) * HID + n];
            wcat[(size_t)n * 512 + k] = (u16)f2b(v);
        } else if (idx < PACK_N + WCAT_N + W1CAT_N) {
            int i2 = idx - PACK_N - WCAT_N;
            int n = i2 >> 5, k = i2 & 31;
            float v = 0.f;
            if (k < IND) v = W1l[k * HID + n];
            else if (k >= 16 && k < 16 + IND) v = W1r[(k - 16) * HID + n];
            w1cat[(size_t)n * 32 + k] = (u16)f2b(v);
        } else if (idx < PREP_TOT) {
            int g = idx - PACK_N - WCAT_N - W1CAT_N;
            int lo = 0, hi = N_N;
            while (lo < hi) { int mid = (lo + hi) >> 1; if (batch[mid] < g) lo = mid + 1; else hi = mid; }
            int lo2 = lo, hi2 = N_N;
            while (lo2 < hi2) { int mid = (lo2 + hi2) >> 1; if (batch[mid] < g + 1) lo2 = mid + 1; else hi2 = mid; }
            gcnt[g] = (float)(lo2 - lo);
        }
        return;
    }
    int base = blockIdx.x * CH3;
    for (int i = t; i < NBUK; i += 512) hist[i] = 0;
    __syncthreads();
#pragma unroll
    for (int i = 0; i < 16; i++) {
        int e = base + i * 512 + t;
        if (e < N_E) atomicAdd(&hist[ei[N_E + e] >> 8], 1);
    }
    __syncthreads();
    sc[t] = (t < NBUK) ? hist[t] : 0;
    __syncthreads();
    for (int off = 1; off < 512; off <<= 1) {
        int v = (t >= off) ? sc[t - off] : 0;
        __syncthreads();
        sc[t] += v;
        __syncthreads();
    }
    if (t < NBUK) lcur[t] = sc[t] - hist[t];   // exclusive base within stage
    __syncthreads();
#pragma unroll
    for (int i = 0; i < 16; i++) {
        int e = base + i * 512 + t;
        if (e < N_E) {
            int d = ei[N_E + e];
            int s = ei[e];
            int b = d >> 8;
            int p = atomicAdd(&lcur[b], 1);
            stage[p] = (u32)s | ((u32)(d & 255) << 17);
            bstage[p] = (u16)b;
        }
    }
    __syncthreads();
    if (t < NBUK) {
        int c = hist[t];
        int o = c ? atomicAdd(&gcur[t * 16], c) : 0;
        gbase[t] = t * CAP + o - (sc[t] - hist[t]);   // so global = gbase[b] + p
    }
    int blockcnt = sc[511];
    __syncthreads();
#pragma unroll
    for (int i = 0; i < 16; i++) {
        int p = i * 512 + t;
        if (p < blockcnt) {
            int b = bstage[p];
            ebuf[gbase[b] + p] = stage[p];
        }
    }
}

// ---- per-bucket counting sort -> csrc, deg, rowp (static bases; 512 threads:
// the two 4096-element edge passes run in half the rounds of the 256-thr version) ----
__global__ __launch_bounds__(512) void k_sort(const u32* __restrict__ ebuf, const int* __restrict__ gcur,
                                              int* __restrict__ csrc, int* __restrict__ deg,
                                              int* __restrict__ rowp) {
    __shared__ int degL[256];
    __shared__ int sc[256];
    __shared__ int curL[256];
    int t = threadIdx.x;
    int b = blockIdx.x;
    int bs = b * CAP;
    int be = bs + gcur[b * 16];
    if (t < 256) degL[t] = 0;
    __syncthreads();
    for (int e = bs + t; e < be; e += 512)
        atomicAdd(&degL[ebuf[e] >> 17], 1);
    __syncthreads();
    if (t < 256) sc[t] = degL[t];
    __syncthreads();
    for (int off = 1; off < 256; off <<= 1) {
        int v = (t >= off && t < 256) ? sc[t - off] : 0;
        __syncthreads();
        if (t < 256) sc[t] += v;
        __syncthreads();
    }
    if (t < 256) {
        int myDeg = degL[t];
        int excl = sc[t] - myDeg;
        int node = (b << 8) + t;       // < 100096; deg=0 for node >= N_N
        deg[node] = myDeg;
        rowp[node] = bs + excl;
        curL[t] = bs + excl;
    }
    __syncthreads();
    for (int e = bs + t; e < be; e += 512) {
        u32 w = ebuf[e];
        int p = atomicAdd(&curL[w >> 17], 1);
        csrc[p] = (int)(w & 0x1FFFFu);
    }
}

// ---- layer 1: gather (8 lanes/edge, unroll-2) + MFMA matmul ----
__global__ __launch_bounds__(256) void k_layer1(const u16* __restrict__ xpb,
                                                const int* __restrict__ rowp, const int* __restrict__ deg,
                                                const int* __restrict__ csrc,
                                                const u16* __restrict__ w1cat, const float* __restrict__ b1,
                                                u16* __restrict__ h1b) {
    __shared__ u16 As[16][32];       // [node][k]: k0..15 = mean(xp) (14,15=0), k16..31 = own row
    __shared__ u16 outS[16][256];    // D staging for coalesced writeout
    int tid = threadIdx.x;
    int wave = tid >> 6, lane = tid & 63;
    int fp = lane & 7;          // feature pair 0..7
    int eg = lane >> 3;         // edge group 0..7
#pragma unroll
    for (int nn = 0; nn < 4; nn++) {
        int s = wave * 4 + nn;
        int node = blockIdx.x * 16 + s;     // grid covers exactly N_N
        int st = rowp[node], dg = deg[node];
        int end = st + dg;
        float a0 = 0.f, a1 = 0.f, b0 = 0.f, b1v = 0.f;
        int e = st + eg;
        for (; e + 8 < end; e += 16) {      // unroll-2: both csrc loads independent
            int nb1 = csrc[e];
            int nb2 = csrc[e + 8];
            u32 v1 = *(const u32*)(xpb + (size_t)nb1 * 16 + fp * 2);
            u32 v2 = *(const u32*)(xpb + (size_t)nb2 * 16 + fp * 2);
            a0 += __uint_as_float(v1 << 16);
            a1 += __uint_as_float(v1 & 0xFFFF0000u);
            b0 += __uint_as_float(v2 << 16);
            b1v += __uint_as_float(v2 & 0xFFFF0000u);
        }
        if (e < end) {
            int nb = csrc[e];
            u32 v = *(const u32*)(xpb + (size_t)nb * 16 + fp * 2);
            a0 += __uint_as_float(v << 16);
            a1 += __uint_as_float(v & 0xFFFF0000u);
        }
        a0 += b0; a1 += b1v;
        if (eg == 1) {   // own row is already bf16: copy pair directly (k 16..31)
            *(u32*)&As[s][16 + fp * 2] = *(const u32*)(xpb + (size_t)node * 16 + fp * 2);
        }
#pragma unroll
        for (int off = 32; off >= 8; off >>= 1) {
            a0 += __shfl_down(a0, off);
            a1 += __shfl_down(a1, off);
        }
        if (eg == 0) {
            float inv = 1.f / (float)max(dg, 1);
            *(u32*)&As[s][fp * 2] = f2b(a0 * inv) | (f2b(a1 * inv) << 16);
        }
    }
    __syncthreads();
    // ---- MFMA phase: wave w covers output feats [w*64, w*64+64) as 4 16x16 tiles ----
    int quad = lane >> 4, m16 = lane & 15;
    bf16x8 afrag = *(const bf16x8*)&As[m16][quad * 8];
#pragma unroll
    for (int u = 0; u < 4; u++) {
        int feat = wave * 64 + u * 16 + m16;
        bf16x8 bfrag = *(const bf16x8*)(w1cat + (size_t)feat * 32 + quad * 8);
        f32x4 d = {0.f, 0.f, 0.f, 0.f};
        d = __builtin_amdgcn_mfma_f32_16x16x32_bf16(afrag, bfrag, d, 0, 0, 0);
        float bj = b1[feat];
#pragma unroll
        for (int i = 0; i < 4; i++) {
            int row = quad * 4 + i;          // node within tile
            outS[row][feat] = (u16)f2b(fmaxf(d[i] + bj, 0.f));
        }
    }
    __syncthreads();
    // ---- coalesced writeout: thread t -> node t>>4, 32B chunk t&15 ----
    int r = tid >> 4, c = tid & 15;
    uint4* dst = (uint4*)(h1b + ((size_t)(blockIdx.x * 16 + r)) * HID + c * 16);
    dst[0] = *(const uint4*)&outS[r][c * 16];
    dst[1] = *(const uint4*)&outS[r][c * 16 + 8];
}

// ---- layer-2 mean aggregation: 1 wave/node, 4 rows in flight; split into two
// half-grid launches for top-5 visibility (wall: ~3.9 TB/s scattered-gather) ----
__global__ __launch_bounds__(256) void k_agg(const u16* __restrict__ h1b, const int* __restrict__ rowp,
                                             const int* __restrict__ deg, const int* __restrict__ csrc,
                                             u16* __restrict__ mean1b, int nodeBase) {
    int tid = threadIdx.x;
    int node = nodeBase + blockIdx.x * 4 + (tid >> 6);
    int lane = tid & 63;
    int half = lane >> 5, l32 = lane & 31;
    int st = rowp[node], dg = deg[node];
    int end = st + dg;
    const size_t roff = (size_t)l32 * 8;
    float accA[8] = {}, accB[8] = {};
    int e = st + half;
    for (; e + 2 < end; e += 4) {
        int nb1 = csrc[e];
        int nb2 = csrc[e + 2];
        uint4 v1 = *(const uint4*)(h1b + (size_t)nb1 * HID + roff);
        uint4 v2 = *(const uint4*)(h1b + (size_t)nb2 * HID + roff);
        ADD8(accA, v1);
        ADD8(accB, v2);
    }
    if (e < end) {
        int nb = csrc[e];
        uint4 v = *(const uint4*)(h1b + (size_t)nb * HID + roff);
        ADD8(accA, v);
    }
    float acc[8];
#pragma unroll
    for (int j = 0; j < 8; j++) acc[j] = accA[j] + accB[j];
#pragma unroll
    for (int j = 0; j < 8; j++) acc[j] += __shfl_down(acc[j], 32);
    if (lane < 32) {
        float inv = 1.f / (float)max(dg, 1);
        uint4 o;
        o.x = f2b(acc[0] * inv) | (f2b(acc[1] * inv) << 16);
        o.y = f2b(acc[2] * inv) | (f2b(acc[3] * inv) << 16);
        o.z = f2b(acc[4] * inv) | (f2b(acc[5] * inv) << 16);
        o.w = f2b(acc[6] * inv) | (f2b(acc[7] * inv) << 16);
        *(uint4*)(mean1b + (size_t)node * HID + roff) = o;
    }
}

// ---- layer 2 (BM=128, Bs double-kt — ~24 us): direct-global A-frags + register
// prefetch; fused relu + Wout-dot + pool atomic ----
__global__ __launch_bounds__(256, 2) void k_layer2(const u16* __restrict__ mean1b, const u16* __restrict__ h1b,
                                                   const u16* __restrict__ wcat, const float* __restrict__ b2,
                                                   const int* __restrict__ batch, const float* __restrict__ Wout,
                                                   float* __restrict__ outsum) {
    __shared__ u16 Bs[2][256][40];
    int tid = threadIdx.x;
    int wave = tid >> 6, lane = tid & 63;
    int quad = lane >> 4, m16 = lane & 15;
    int bm = blockIdx.x;
    const size_t r0 = (size_t)(bm * 128 + wave * 32 + m16) * HID + quad * 8;
    const size_t r1 = r0 + 16 * HID;
    f32x4 acc[2][16] = {};
    uint4 a0 = *(const uint4*)(mean1b + r0);
    uint4 a1 = *(const uint4*)(mean1b + r1);
    for (int kt2 = 0; kt2 < 8; kt2++) {
        __syncthreads();
#pragma unroll
        for (int h = 0; h < 2; h++) {
            int kt = kt2 * 2 + h;
#pragma unroll
            for (int i = 0; i < 4; i++) {
                int cidx = tid + 256 * i;
                int n = cidx >> 2, kc = cidx & 3;
                *(uint4*)&Bs[h][n][kc * 8] =
                    *(const uint4*)(wcat + (size_t)n * 512 + kt * 32 + kc * 8);
            }
        }
        __syncthreads();
#pragma unroll
        for (int h = 0; h < 2; h++) {
            int kt = kt2 * 2 + h;
            uint4 cur0 = a0, cur1 = a1;
            if (kt < 15) {
                int kg = (kt + 1) * 32;
                const u16* An = (kg < 256) ? (mean1b + kg) : (h1b + (kg - 256));
                a0 = *(const uint4*)(An + r0);
                a1 = *(const uint4*)(An + r1);
            }
            bf16x8 af0 = __builtin_bit_cast(bf16x8, cur0);
            bf16x8 af1 = __builtin_bit_cast(bf16x8, cur1);
#pragma unroll
            for (int u = 0; u < 16; u++) {
                bf16x8 bf = *(const bf16x8*)&Bs[h][u * 16 + m16][quad * 8];
                acc[0][u] = __builtin_amdgcn_mfma_f32_16x16x32_bf16(af0, bf, acc[0][u], 0, 0, 0);
                acc[1][u] = __builtin_amdgcn_mfma_f32_16x16x32_bf16(af1, bf, acc[1][u], 0, 0, 0);
            }
        }
    }
    float wo[16], bb[16];
#pragma unroll
    for (int u = 0; u < 16; u++) { int col = u * 16 + m16; wo[u] = Wout[col]; bb[u] = b2[col]; }
#pragma unroll
    for (int t = 0; t < 2; t++) {
#pragma unroll
        for (int i = 0; i < 4; i++) {
            float p = 0.f;
#pragma unroll
            for (int u = 0; u < 16; u++)
                p = fmaf(fmaxf(acc[t][u][i] + bb[u], 0.f), wo[u], p);
#pragma unroll
            for (int off = 8; off > 0; off >>= 1) p += __shfl_down(p, off, 16);
            int row = bm * 128 + wave * 32 + t * 16 + quad * 4 + i;
            if (m16 == 0 && row < N_N) atomicAdd(&outsum[batch[row]], p);
        }
    }
}

// ---- output head ----
__global__ __launch_bounds__(256) void k_out(const float* __restrict__ outsum, const float* __restrict__ gcnt,
                                             const float* __restrict__ bout, float* __restrict__ out) {
    int g = blockIdx.x * 256 + threadIdx.x;
    if (g < N_G) out[g] = outsum[g] / fmaxf(gcnt[g], 1.f) + bout[0];
}

extern "C" void kernel_launch(void* const* d_in, const int* in_sizes, int n_in,
                              void* d_out, int out_size, void* d_ws, size_t ws_size,
                              hipStream_t stream) {
    const float* x    = (const float*)d_in[0];
    const float* pos  = (const float*)d_in[1];
    const int*   ei   = (const int*)d_in[2];
    const int*   batch= (const int*)d_in[3];
    const float* W1l  = (const float*)d_in[4];
    const float* b1   = (const float*)d_in[5];
    const float* W1r  = (const float*)d_in[6];
    const float* W2l  = (const float*)d_in[7];
    const float* b2   = (const float*)d_in[8];
    const float* W2r  = (const float*)d_in[9];
    const float* Wout = (const float*)d_in[10];
    const float* bout = (const float*)d_in[11];
    float* out = (float*)d_out;
    float* ws  = (float*)d_ws;

    float* outs  = ws + OFF_OUTS;
    int*   gcur  = (int*)(ws + OFF_GCUR);
    float* gcnt  = ws + OFF_GCNT;
    int*   rowp  = (int*)(ws + OFF_ROWP);
    int*   deg   = (int*)(ws + OFF_DEG);
    u32*   ebuf  = (u32*)(ws + OFF_EBUF);
    int*   csrc  = (int*)(ws + OFF_CSRC);
    u16*   h1b   = (u16*)(ws + OFF_H1B);
    u16*   wcat  = (u16*)(ws + OFF_WCAT);
    u16*   xpb   = (u16*)(ws + OFF_XP);
    u16*   mean1b= (u16*)(ws + OFF_MEAN1B);
    u16*   w1cat = (u16*)(ws + OFF_W1CAT);

    hipMemsetAsync(d_ws, 0, ZERO_BYTES, stream);
    k_bfill_prep<<<NFB + PREP_BLKS, 512, 0, stream>>>(
        ei, gcur, ebuf, x, pos, batch, W2l, W2r, W1l, W1r, xpb, gcnt, wcat, w1cat);
    k_sort  <<<NBUK, 512, 0, stream>>>(ebuf, gcur, csrc, deg, rowp);
    k_layer1<<<N_N / 16, 256, 0, stream>>>(xpb, rowp, deg, csrc, w1cat, b1, h1b);
    k_agg   <<<N_N / 8, 256, 0, stream>>>(h1b, rowp, deg, csrc, mean1b, 0);
    k_agg   <<<N_N / 8, 256, 0, stream>>>(h1b, rowp, deg, csrc, mean1b, N_N / 2);
    k_layer2<<<(N_N + 127) / 128, 256, 0, stream>>>(mean1b, h1b, wcat, b2, batch, Wout, outs);
    k_out   <<<(N_G + 255) / 256, 256, 0, stream>>>(outs, gcnt, bout, out);
}

// Round 20
// 323.331 us; speedup vs baseline: 1.0182x; 1.0182x over previous
//
#include <hip/hip_runtime.h>

#define N_N 100000
#define N_E 1600000
#define N_G 5000
#define HID 256
#define IND 14

#define NBUK 391      // buckets: dst>>8, 256 nodes each (391*256 = 100096)
#define CAP 5120      // static per-bucket capacity (E[cnt]=4096, sigma~64; +16 sigma)
#define CH3 8192      // edges per binning block (512 threads)
#define NFB 196       // ceil(N_E/CH3)

typedef __bf16 bf16x8 __attribute__((ext_vector_type(8)));
typedef float f32x4 __attribute__((ext_vector_type(4)));
typedef unsigned short u16;
typedef unsigned int u32;

// ---- workspace layout (units of 4 bytes) ----
constexpr size_t OFF_OUTS  = 0;          // float[5120]   (zeroed)
constexpr size_t OFF_GCUR  = 5120;       // int[391*16]   (zeroed, 64B-padded cursors)
constexpr size_t ZERO_END  = 11520;
constexpr size_t ZERO_BYTES = ZERO_END * 4;
constexpr size_t OFF_GCNT  = 11520;      // float[5120] (fully written)
constexpr size_t OFF_ROWP  = 16640;      // int[100096]
constexpr size_t OFF_DEG   = 116736;     // int[100096]
constexpr size_t OFF_EBUF  = 216832;     // u32[391*5120]
constexpr size_t OFF_CSRC  = 2218752;    // int[391*5120]
constexpr size_t OFF_H1B   = 4220672;    // bf16[100096*256] -> ends 17032960
constexpr size_t OFF_WCAT  = 17032960;   // bf16[256*512]    -> ends 17098496
constexpr size_t OFF_XP    = 17098496;   // bf16[N*16]       -> ends 17898496
constexpr size_t OFF_MEAN1B= 17898496;   // bf16[100096*256] -> ends 30710784
constexpr size_t OFF_W1CAT = 30710784;   // bf16[256*32]     -> ends 30714880
// end = 30714880 floats ~= 123 MB

__device__ __forceinline__ u32 f2b(float f) {
    u32 u = __float_as_uint(f);
    u32 r = u + 0x7FFFu + ((u >> 16) & 1u);
    return r >> 16;
}

#define ADD8(acc, v) do { \
    acc[0] += __uint_as_float(v.x << 16); \
    acc[1] += __uint_as_float(v.x & 0xFFFF0000u); \
    acc[2] += __uint_as_float(v.y << 16); \
    acc[3] += __uint_as_float(v.y & 0xFFFF0000u); \
    acc[4] += __uint_as_float(v.z << 16); \
    acc[5] += __uint_as_float(v.z & 0xFFFF0000u); \
    acc[6] += __uint_as_float(v.w << 16); \
    acc[7] += __uint_as_float(v.w & 0xFFFF0000u); \
} while (0)

// ---- MERGED binning + prep; scan via wave-shuffle (2 barriers vs 18) ----
#define PACK_N (N_N * 16)
#define WCAT_N (256 * 512)
#define W1CAT_N (256 * 32)
#define PREP_TOT (PACK_N + WCAT_N + W1CAT_N + N_G)
#define PREP_BLKS ((PREP_TOT + 511) / 512)      // 3407
__global__ __launch_bounds__(512) void k_bfill_prep(const int* __restrict__ ei, int* __restrict__ gcur,
                                                    u32* __restrict__ ebuf,
                                                    const float* __restrict__ x, const float* __restrict__ pos,
                                                    const int* __restrict__ batch,
                                                    const float* __restrict__ W2l, const float* __restrict__ W2r,
                                                    const float* __restrict__ W1l, const float* __restrict__ W1r,
                                                    u16* __restrict__ xpb, float* __restrict__ gcnt,
                                                    u16* __restrict__ wcat, u16* __restrict__ w1cat) {
    __shared__ int hist[NBUK];
    __shared__ int lcur[NBUK];
    __shared__ int gbase[NBUK];
    __shared__ int wsum[8];
    __shared__ u32 stage[CH3];
    __shared__ u16 bstage[CH3];
    int t = threadIdx.x;
    if (blockIdx.x >= NFB) {
        int idx = (blockIdx.x - NFB) * 512 + t;
        if (idx < PACK_N) {
            int n = idx >> 4, f = idx & 15;
            float v = 0.f;
            if (f < 11) v = x[n * 11 + f];
            else if (f < 14) v = pos[n * 3 + (f - 11)];
            xpb[idx] = (u16)f2b(v);
        } else if (idx < PACK_N + WCAT_N) {
            int i2 = idx - PACK_N;
            int n = i2 >> 9, k = i2 & 511;
            float v = (k < 256) ? W2l[k * HID + n] : W2r[(k - 256) * HID + n];
            wcat[(size_t)n * 512 + k] = (u16)f2b(v);
        } else if (idx < PACK_N + WCAT_N + W1CAT_N) {
            int i2 = idx - PACK_N - WCAT_N;
            int n = i2 >> 5, k = i2 & 31;
            float v = 0.f;
            if (k < IND) v = W1l[k * HID + n];
            else if (k >= 16 && k < 16 + IND) v = W1r[(k - 16) * HID + n];
            w1cat[(size_t)n * 32 + k] = (u16)f2b(v);
        } else if (idx < PREP_TOT) {
            int g = idx - PACK_N - WCAT_N - W1CAT_N;
            int lo = 0, hi = N_N;
            while (lo < hi) { int mid = (lo + hi) >> 1; if (batch[mid] < g) lo = mid + 1; else hi = mid; }
            int lo2 = lo, hi2 = N_N;
            while (lo2 < hi2) { int mid = (lo2 + hi2) >> 1; if (batch[mid] < g + 1) lo2 = mid + 1; else hi2 = mid; }
            gcnt[g] = (float)(lo2 - lo);
        }
        return;
    }
    int lane = t & 63, wv = t >> 6;
    int base = blockIdx.x * CH3;
    for (int i = t; i < NBUK; i += 512) hist[i] = 0;
    __syncthreads();
#pragma unroll
    for (int i = 0; i < 16; i++) {
        int e = base + i * 512 + t;
        if (e < N_E) atomicAdd(&hist[ei[N_E + e] >> 8], 1);
    }
    __syncthreads();
    // wave-shuffle inclusive scan of hist over 512 lanes
    int v = (t < NBUK) ? hist[t] : 0;
    int inc = v;
#pragma unroll
    for (int off = 1; off < 64; off <<= 1) {
        int u = __shfl_up(inc, off, 64);
        if (lane >= off) inc += u;
    }
    if (lane == 63) wsum[wv] = inc;
    __syncthreads();
    int pre = 0;
    for (int i = 0; i < wv; i++) pre += wsum[i];
    int inclusive = inc + pre;
    int excl = inclusive - v;                 // exclusive base within stage (reg-saved)
    if (t < NBUK) lcur[t] = excl;
    int blockcnt = 0;
#pragma unroll
    for (int i = 0; i < 8; i++) blockcnt += wsum[i];
    __syncthreads();
#pragma unroll
    for (int i = 0; i < 16; i++) {
        int e = base + i * 512 + t;
        if (e < N_E) {
            int d = ei[N_E + e];
            int s = ei[e];
            int b = d >> 8;
            int p = atomicAdd(&lcur[b], 1);
            stage[p] = (u32)s | ((u32)(d & 255) << 17);
            bstage[p] = (u16)b;
        }
    }
    __syncthreads();
    if (t < NBUK) {
        int c = hist[t];
        int o = c ? atomicAdd(&gcur[t * 16], c) : 0;
        gbase[t] = t * CAP + o - excl;        // so global = gbase[b] + p
    }
    __syncthreads();
#pragma unroll
    for (int i = 0; i < 16; i++) {
        int p = i * 512 + t;
        if (p < blockcnt) {
            int b = bstage[p];
            ebuf[gbase[b] + p] = stage[p];
        }
    }
}

// ---- per-bucket counting sort (static bases; wave-shuffle scan, 4 barriers) ----
__global__ __launch_bounds__(256) void k_sort(const u32* __restrict__ ebuf, const int* __restrict__ gcur,
                                              int* __restrict__ csrc, int* __restrict__ deg,
                                              int* __restrict__ rowp) {
    __shared__ int degL[256];
    __shared__ int curL[256];
    __shared__ int wsum[4];
    int t = threadIdx.x;
    int lane = t & 63, wv = t >> 6;
    int b = blockIdx.x;
    int bs = b * CAP;
    int be = bs + gcur[b * 16];
    degL[t] = 0;
    __syncthreads();
    for (int e = bs + t; e < be; e += 256)
        atomicAdd(&degL[ebuf[e] >> 17], 1);
    __syncthreads();
    int myDeg = degL[t];
    int inc = myDeg;
#pragma unroll
    for (int off = 1; off < 64; off <<= 1) {
        int u = __shfl_up(inc, off, 64);
        if (lane >= off) inc += u;
    }
    if (lane == 63) wsum[wv] = inc;
    __syncthreads();
    int pre = 0;
    for (int i = 0; i < wv; i++) pre += wsum[i];
    int excl = inc + pre - myDeg;
    int node = (b << 8) + t;       // < 100096; deg=0 for node >= N_N
    deg[node] = myDeg;
    rowp[node] = bs + excl;
    curL[t] = bs + excl;
    __syncthreads();
    for (int e = bs + t; e < be; e += 256) {
        u32 w = ebuf[e];
        int p = atomicAdd(&curL[w >> 17], 1);
        csrc[p] = (int)(w & 0x1FFFFu);
    }
}

// ---- layer 1: gather (8 lanes/edge, unroll-2) + MFMA matmul ----
__global__ __launch_bounds__(256) void k_layer1(const u16* __restrict__ xpb,
                                                const int* __restrict__ rowp, const int* __restrict__ deg,
                                                const int* __restrict__ csrc,
                                                const u16* __restrict__ w1cat, const float* __restrict__ b1,
                                                u16* __restrict__ h1b) {
    __shared__ u16 As[16][32];       // [node][k]: k0..15 = mean(xp) (14,15=0), k16..31 = own row
    __shared__ u16 outS[16][256];    // D staging for coalesced writeout
    int tid = threadIdx.x;
    int wave = tid >> 6, lane = tid & 63;
    int fp = lane & 7;          // feature pair 0..7
    int eg = lane >> 3;         // edge group 0..7
#pragma unroll
    for (int nn = 0; nn < 4; nn++) {
        int s = wave * 4 + nn;
        int node = blockIdx.x * 16 + s;     // grid covers exactly N_N
        int st = rowp[node], dg = deg[node];
        int end = st + dg;
        float a0 = 0.f, a1 = 0.f, b0 = 0.f, b1v = 0.f;
        int e = st + eg;
        for (; e + 8 < end; e += 16) {      // unroll-2: both csrc loads independent
            int nb1 = csrc[e];
            int nb2 = csrc[e + 8];
            u32 v1 = *(const u32*)(xpb + (size_t)nb1 * 16 + fp * 2);
            u32 v2 = *(const u32*)(xpb + (size_t)nb2 * 16 + fp * 2);
            a0 += __uint_as_float(v1 << 16);
            a1 += __uint_as_float(v1 & 0xFFFF0000u);
            b0 += __uint_as_float(v2 << 16);
            b1v += __uint_as_float(v2 & 0xFFFF0000u);
        }
        if (e < end) {
            int nb = csrc[e];
            u32 v = *(const u32*)(xpb + (size_t)nb * 16 + fp * 2);
            a0 += __uint_as_float(v << 16);
            a1 += __uint_as_float(v & 0xFFFF0000u);
        }
        a0 += b0; a1 += b1v;
        if (eg == 1) {   // own row is already bf16: copy pair directly (k 16..31)
            *(u32*)&As[s][16 + fp * 2] = *(const u32*)(xpb + (size_t)node * 16 + fp * 2);
        }
#pragma unroll
        for (int off = 32; off >= 8; off >>= 1) {
            a0 += __shfl_down(a0, off);
            a1 += __shfl_down(a1, off);
        }
        if (eg == 0) {
            float inv = 1.f / (float)max(dg, 1);
            *(u32*)&As[s][fp * 2] = f2b(a0 * inv) | (f2b(a1 * inv) << 16);
        }
    }
    __syncthreads();
    // ---- MFMA phase: wave w covers output feats [w*64, w*64+64) as 4 16x16 tiles ----
    int quad = lane >> 4, m16 = lane & 15;
    bf16x8 afrag = *(const bf16x8*)&As[m16][quad * 8];
#pragma unroll
    for (int u = 0; u < 4; u++) {
        int feat = wave * 64 + u * 16 + m16;
        bf16x8 bfrag = *(const bf16x8*)(w1cat + (size_t)feat * 32 + quad * 8);
        f32x4 d = {0.f, 0.f, 0.f, 0.f};
        d = __builtin_amdgcn_mfma_f32_16x16x32_bf16(afrag, bfrag, d, 0, 0, 0);
        float bj = b1[feat];
#pragma unroll
        for (int i = 0; i < 4; i++) {
            int row = quad * 4 + i;          // node within tile
            outS[row][feat] = (u16)f2b(fmaxf(d[i] + bj, 0.f));
        }
    }
    __syncthreads();
    // ---- coalesced writeout: thread t -> node t>>4, 32B chunk t&15 ----
    int r = tid >> 4, c = tid & 15;
    uint4* dst = (uint4*)(h1b + ((size_t)(blockIdx.x * 16 + r)) * HID + c * 16);
    dst[0] = *(const uint4*)&outS[r][c * 16];
    dst[1] = *(const uint4*)&outS[r][c * 16 + 8];
}

// ---- layer-2 mean aggregation: 1 wave/node, 4 rows in flight (pinned at the
// ~3.9 TB/s scattered-gather service wall; R7/R10/R16 falsified alternatives) ----
__global__ __launch_bounds__(256) void k_agg(const u16* __restrict__ h1b, const int* __restrict__ rowp,
                                             const int* __restrict__ deg, const int* __restrict__ csrc,
                                             u16* __restrict__ mean1b) {
    int tid = threadIdx.x;
    int node = blockIdx.x * 4 + (tid >> 6);
    int lane = tid & 63;
    int half = lane >> 5, l32 = lane & 31;
    int st = rowp[node], dg = deg[node];
    int end = st + dg;
    const size_t roff = (size_t)l32 * 8;
    float accA[8] = {}, accB[8] = {};
    int e = st + half;
    for (; e + 2 < end; e += 4) {
        int nb1 = csrc[e];
        int nb2 = csrc[e + 2];
        uint4 v1 = *(const uint4*)(h1b + (size_t)nb1 * HID + roff);
        uint4 v2 = *(const uint4*)(h1b + (size_t)nb2 * HID + roff);
        ADD8(accA, v1);
        ADD8(accB, v2);
    }
    if (e < end) {
        int nb = csrc[e];
        uint4 v = *(const uint4*)(h1b + (size_t)nb * HID + roff);
        ADD8(accA, v);
    }
    float acc[8];
#pragma unroll
    for (int j = 0; j < 8; j++) acc[j] = accA[j] + accB[j];
#pragma unroll
    for (int j = 0; j < 8; j++) acc[j] += __shfl_down(acc[j], 32);
    if (lane < 32) {
        float inv = 1.f / (float)max(dg, 1);
        uint4 o;
        o.x = f2b(acc[0] * inv) | (f2b(acc[1] * inv) << 16);
        o.y = f2b(acc[2] * inv) | (f2b(acc[3] * inv) << 16);
        o.z = f2b(acc[4] * inv) | (f2b(acc[5] * inv) << 16);
        o.w = f2b(acc[6] * inv) | (f2b(acc[7] * inv) << 16);
        *(uint4*)(mean1b + (size_t)node * HID + roff) = o;
    }
}

// ---- layer 2 (BM=128, Bs double-kt — ~24 us): direct-global A-frags + register
// prefetch; fused relu + Wout-dot + pool atomic ----
__global__ __launch_bounds__(256, 2) void k_layer2(const u16* __restrict__ mean1b, const u16* __restrict__ h1b,
                                                   const u16* __restrict__ wcat, const float* __restrict__ b2,
                                                   const int* __restrict__ batch, const float* __restrict__ Wout,
                                                   float* __restrict__ outsum) {
    __shared__ u16 Bs[2][256][40];
    int tid = threadIdx.x;
    int wave = tid >> 6, lane = tid & 63;
    int quad = lane >> 4, m16 = lane & 15;
    int bm = blockIdx.x;
    const size_t r0 = (size_t)(bm * 128 + wave * 32 + m16) * HID + quad * 8;
    const size_t r1 = r0 + 16 * HID;
    f32x4 acc[2][16] = {};
    uint4 a0 = *(const uint4*)(mean1b + r0);
    uint4 a1 = *(const uint4*)(mean1b + r1);
    for (int kt2 = 0; kt2 < 8; kt2++) {
        __syncthreads();
#pragma unroll
        for (int h = 0; h < 2; h++) {
            int kt = kt2 * 2 + h;
#pragma unroll
            for (int i = 0; i < 4; i++) {
                int cidx = tid + 256 * i;
                int n = cidx >> 2, kc = cidx & 3;
                *(uint4*)&Bs[h][n][kc * 8] =
                    *(const uint4*)(wcat + (size_t)n * 512 + kt * 32 + kc * 8);
            }
        }
        __syncthreads();
#pragma unroll
        for (int h = 0; h < 2; h++) {
            int kt = kt2 * 2 + h;
            uint4 cur0 = a0, cur1 = a1;
            if (kt < 15) {
                int kg = (kt + 1) * 32;
                const u16* An = (kg < 256) ? (mean1b + kg) : (h1b + (kg - 256));
                a0 = *(const uint4*)(An + r0);
                a1 = *(const uint4*)(An + r1);
            }
            bf16x8 af0 = __builtin_bit_cast(bf16x8, cur0);
            bf16x8 af1 = __builtin_bit_cast(bf16x8, cur1);
#pragma unroll
            for (int u = 0; u < 16; u++) {
                bf16x8 bf = *(const bf16x8*)&Bs[h][u * 16 + m16][quad * 8];
                acc[0][u] = __builtin_amdgcn_mfma_f32_16x16x32_bf16(af0, bf, acc[0][u], 0, 0, 0);
                acc[1][u] = __builtin_amdgcn_mfma_f32_16x16x32_bf16(af1, bf, acc[1][u], 0, 0, 0);
            }
        }
    }
    float wo[16], bb[16];
#pragma unroll
    for (int u = 0; u < 16; u++) { int col = u * 16 + m16; wo[u] = Wout[col]; bb[u] = b2[col]; }
#pragma unroll
    for (int t = 0; t < 2; t++) {
#pragma unroll
        for (int i = 0; i < 4; i++) {
            float p = 0.f;
#pragma unroll
            for (int u = 0; u < 16; u++)
                p = fmaf(fmaxf(acc[t][u][i] + bb[u], 0.f), wo[u], p);
#pragma unroll
            for (int off = 8; off > 0; off >>= 1) p += __shfl_down(p, off, 16);
            int row = bm * 128 + wave * 32 + t * 16 + quad * 4 + i;
            if (m16 == 0 && row < N_N) atomicAdd(&outsum[batch[row]], p);
        }
    }
}

// ---- output head ----
__global__ __launch_bounds__(256) void k_out(const float* __restrict__ outsum, const float* __restrict__ gcnt,
                                             const float* __restrict__ bout, float* __restrict__ out) {
    int g = blockIdx.x * 256 + threadIdx.x;
    if (g < N_G) out[g] = outsum[g] / fmaxf(gcnt[g], 1.f) + bout[0];
}

extern "C" void kernel_launch(void* const* d_in, const int* in_sizes, int n_in,
                              void* d_out, int out_size, void* d_ws, size_t ws_size,
                              hipStream_t stream) {
    const float* x    = (const float*)d_in[0];
    const float* pos  = (const float*)d_in[1];
    const int*   ei   = (const int*)d_in[2];
    const int*   batch= (const int*)d_in[3];
    const float* W1l  = (const float*)d_in[4];
    const float* b1   = (const float*)d_in[5];
    const float* W1r  = (const float*)d_in[6];
    const float* W2l  = (const float*)d_in[7];
    const float* b2   = (const float*)d_in[8];
    const float* W2r  = (const float*)d_in[9];
    const float* Wout = (const float*)d_in[10];
    const float* bout = (const float*)d_in[11];
    float* out = (float*)d_out;
    float* ws  = (float*)d_ws;

    float* outs  = ws + OFF_OUTS;
    int*   gcur  = (int*)(ws + OFF_GCUR);
    float* gcnt  = ws + OFF_GCNT;
    int*   rowp  = (int*)(ws + OFF_ROWP);
    int*   deg   = (int*)(ws + OFF_DEG);
    u32*   ebuf  = (u32*)(ws + OFF_EBUF);
    int*   csrc  = (int*)(ws + OFF_CSRC);
    u16*   h1b   = (u16*)(ws + OFF_H1B);
    u16*   wcat  = (u16*)(ws + OFF_WCAT);
    u16*   xpb   = (u16*)(ws + OFF_XP);
    u16*   mean1b= (u16*)(ws + OFF_MEAN1B);
    u16*   w1cat = (u16*)(ws + OFF_W1CAT);

    hipMemsetAsync(d_ws, 0, ZERO_BYTES, stream);
    k_bfill_prep<<<NFB + PREP_BLKS, 512, 0, stream>>>(
        ei, gcur, ebuf, x, pos, batch, W2l, W2r, W1l, W1r, xpb, gcnt, wcat, w1cat);
    k_sort  <<<NBUK, 256, 0, stream>>>(ebuf, gcur, csrc, deg, rowp);
    k_layer1<<<N_N / 16, 256, 0, stream>>>(xpb, rowp, deg, csrc, w1cat, b1, h1b);
    k_agg   <<<N_N / 4, 256, 0, stream>>>(h1b, rowp, deg, csrc, mean1b);
    k_layer2<<<(N_N + 127) / 128, 256, 0, stream>>>(mean1b, h1b, wcat, b2, batch, Wout, outs);
    k_out   <<<(N_G + 255) / 256, 256, 0, stream>>>(outs, gcnt, bout, out);
}